// Round 1
// baseline (1644.612 us; speedup 1.0000x reference)
//
#include <hip/hip_runtime.h>

// AGMBrain: B=16384, INPUT_DIM=256, N=32 neurons, D=128, 3 steps.
// Round 1: correct fp32 baseline.
//   - 1 wave == 1 batch element (NB=4 per block, 256 threads, grid 4096)
//   - states tile [NB][32][128] f32 in LDS (exactly 64 KB -> 2 blocks/CU)
//   - scores column computed via lane-parallel dot4 + shfl_xor butterfly,
//     broadcast with __shfl and fused straight into register accumulators
//     (no scores array in LDS, no per-j cross-wave dependency)
//   - step 3 computes ONLY neuron row 31 (the only one the output uses)
//   - out row reuses st[b][0] storage for the output GEMM phase

#define NB 4

__global__ __launch_bounds__(256, 2)
void agm_kernel(const float* __restrict__ x,
                const float* __restrict__ W_in,
                const float* __restrict__ b_in,
                const float* __restrict__ ns,
                const float* __restrict__ edge,
                const float* __restrict__ W_rec,
                const float* __restrict__ b_rec,
                const float* __restrict__ W_score,
                const float* __restrict__ b_score,
                float* __restrict__ out_rec,
                float* __restrict__ out_sc)
{
    __shared__ float st[NB][32][128];   // 65536 B

    const int t  = threadIdx.x;
    const int b  = __builtin_amdgcn_readfirstlane(t >> 6); // wave id == local batch
    const int ln = t & 63;
    const long bg = (long)blockIdx.x * NB + b;             // global batch row

    // ---- Phase A: x_t = x[bg] @ W_in + b_in ; st[b][i][:] = ns[i][:] + x_t ----
    {
        const float* xb = x + bg * 256;
        float a0 = b_in[ln], a1 = b_in[ln + 64];
        for (int k = 0; k < 256; k += 4) {
            const float4 xv = *(const float4*)(xb + k);
            a0 += xv.x * W_in[(k+0)*128 + ln];  a1 += xv.x * W_in[(k+0)*128 + 64 + ln];
            a0 += xv.y * W_in[(k+1)*128 + ln];  a1 += xv.y * W_in[(k+1)*128 + 64 + ln];
            a0 += xv.z * W_in[(k+2)*128 + ln];  a1 += xv.z * W_in[(k+2)*128 + 64 + ln];
            a0 += xv.w * W_in[(k+3)*128 + ln];  a1 += xv.w * W_in[(k+3)*128 + 64 + ln];
        }
        for (int i = 0; i < 32; ++i) {
            st[b][i][ln]      = ns[i*128 + ln]      + a0;
            st[b][i][ln + 64] = ns[i*128 + 64 + ln] + a1;
        }
    }
    __syncthreads();

    const int h  = ln >> 5;   // which dot of the pair (i = 2m + h)
    const int q4 = ln & 31;   // float4 index within the 128-long row

    // ---- Steps 1 & 2: full update of all 32 neurons ----
    for (int step = 0; step < 2; ++step) {
        float acc0[32], acc1[32];
        #pragma unroll
        for (int i = 0; i < 32; ++i) { acc0[i] = 0.f; acc1[i] = 0.f; }

        for (int j = 0; j < 32; ++j) {
            // old-states operand for the update (constant over m below)
            const float s0 = st[b][j][ln];
            const float s1 = st[b][j][ln + 64];
            // scores column j: col_i = <edge[i][j][:], st[b][i][:]>, fused accumulate
            #pragma unroll
            for (int m = 0; m < 16; ++m) {
                const int i = 2*m + h;
                const float4 ev = *(const float4*)(edge + (((size_t)(i*32 + j)) << 7) + (q4 << 2));
                const float4 sv = *(const float4*)(&st[b][i][q4 << 2]);
                float s = ev.x*sv.x + ev.y*sv.y + ev.z*sv.z + ev.w*sv.w;
                s += __shfl_xor(s, 1);
                s += __shfl_xor(s, 2);
                s += __shfl_xor(s, 4);
                s += __shfl_xor(s, 8);
                s += __shfl_xor(s, 16);           // all lanes of each half now hold the full dot
                float c0 = __shfl(s, 0);          // col for i = 2m
                float c1 = __shfl(s, 32);         // col for i = 2m+1
                if (2*m     == j) c0 = 0.f;       // off-diagonal mask
                if (2*m + 1 == j) c1 = 0.f;
                acc0[2*m  ] += c0 * s0;  acc1[2*m  ] += c0 * s1;
                acc0[2*m+1] += c1 * s0;  acc1[2*m+1] += c1 * s1;
            }
            __syncthreads();  // keeps the 4 waves j-phase-locked for L1 edge reuse
        }
        // relu + writeback
        #pragma unroll
        for (int i = 0; i < 32; ++i) {
            st[b][i][ln]      = fmaxf(acc0[i], 0.f);
            st[b][i][ln + 64] = fmaxf(acc1[i], 0.f);
        }
        __syncthreads();
    }

    // ---- Step 3: only neuron 31 -> out = relu(scores31 @ states) ----
    {
        float o0 = 0.f, o1 = 0.f;
        #pragma unroll
        for (int m = 0; m < 16; ++m) {
            const int jj = 2*m + h;
            const float4 ev = *(const float4*)(edge + (((size_t)(31*32 + jj)) << 7) + (q4 << 2));
            const float4 sv = *(const float4*)(&st[b][31][q4 << 2]);
            float s = ev.x*sv.x + ev.y*sv.y + ev.z*sv.z + ev.w*sv.w;
            s += __shfl_xor(s, 1);
            s += __shfl_xor(s, 2);
            s += __shfl_xor(s, 4);
            s += __shfl_xor(s, 8);
            s += __shfl_xor(s, 16);
            float c0 = __shfl(s, 0);
            float c1 = __shfl(s, 32);
            if (2*m     == 31) c0 = 0.f;
            if (2*m + 1 == 31) c1 = 0.f;
            o0 += c0 * st[b][2*m  ][ln] + c1 * st[b][2*m+1][ln];
            o1 += c0 * st[b][2*m  ][ln + 64] + c1 * st[b][2*m+1][ln + 64];
        }
        __syncthreads();                 // everyone done reading st[b][...]
        st[b][0][ln]      = fmaxf(o0, 0.f);   // reuse st[b][0] as out row
        st[b][0][ln + 64] = fmaxf(o1, 0.f);
    }
    __syncthreads();

    // ---- Outputs: recreation = out @ W_rec + b_rec ; score = out @ W_score + b_score ----
    {
        const float* ob = &st[b][0][0];
        float r0 = b_rec[ln], r1 = b_rec[ln+64], r2 = b_rec[ln+128], r3 = b_rec[ln+192];
        for (int p = 0; p < 128; ++p) {
            const float ov = ob[p];
            r0 += ov * W_rec[p*256 + ln];
            r1 += ov * W_rec[p*256 + 64  + ln];
            r2 += ov * W_rec[p*256 + 128 + ln];
            r3 += ov * W_rec[p*256 + 192 + ln];
        }
        float* orow = out_rec + bg * 256;
        orow[ln] = r0; orow[ln+64] = r1; orow[ln+128] = r2; orow[ln+192] = r3;

        float s = ob[ln] * W_score[ln] + ob[ln + 64] * W_score[ln + 64];
        s += __shfl_xor(s, 32);
        s += __shfl_xor(s, 16);
        s += __shfl_xor(s, 8);
        s += __shfl_xor(s, 4);
        s += __shfl_xor(s, 2);
        s += __shfl_xor(s, 1);
        if (ln == 0) out_sc[bg] = s + b_score[0];
    }
}

extern "C" void kernel_launch(void* const* d_in, const int* in_sizes, int n_in,
                              void* d_out, int out_size, void* d_ws, size_t ws_size,
                              hipStream_t stream) {
    const float* x     = (const float*)d_in[0];
    const float* W_in  = (const float*)d_in[1];
    const float* bin   = (const float*)d_in[2];
    const float* ns    = (const float*)d_in[3];
    const float* edge  = (const float*)d_in[4];
    const float* W_rec = (const float*)d_in[5];
    const float* brec  = (const float*)d_in[6];
    const float* W_sc  = (const float*)d_in[7];
    const float* b_sc  = (const float*)d_in[8];

    const int B = in_sizes[0] / 256;          // 16384
    float* out = (float*)d_out;               // [B*256] recreation, then [B] score

    agm_kernel<<<dim3(B / NB), dim3(256), 0, stream>>>(
        x, W_in, bin, ns, edge, W_rec, brec, W_sc, b_sc,
        out, out + (size_t)B * 256);
}

// Round 5
// 1147.545 us; speedup vs baseline: 1.4332x; 1.4332x over previous
//
#include <hip/hip_runtime.h>
#include <cstdint>

// AGMBrain: B=16384, INPUT_DIM=256, N=32 neurons, D=128, 3 steps.
// Round 5: single-kernel fp16-MFMA diagnostic baseline.
//   All suspects from r2-r4 removed: ONE kernel, 256 threads, 55KB static LDS
//   (round-1-proven regime), no workspace, no inline asm, no ds_read_*_tr,
//   no multi-kernel ordering. Only new ingredient vs the passing round-1: MFMA.
//   - dual-layout states per batch: st[i][p] (row-major) for part1 B-operand,
//     st_T[p][j] (col-major) for part2 B-operand; both contiguous b128 reads.
//   - edge read fp32 from global (L3-resident), converted to f16 in registers;
//     off_diag mask = per-lane zeroing of the A fragment when row j == i.
//   - per-batch power-of-2 scaling tracked as per-wave int exponent (wave w
//     owns batch w; no cross-wave communication), descaled in fp32 epilogue.
//   - all 3 steps computed identically (no step-3 row-31 specialization).

#define BTOT 16384
#define NBATCH 3

typedef _Float16 f16;
typedef _Float16 f16x8 __attribute__((ext_vector_type(8)));
typedef float f32x4 __attribute__((ext_vector_type(4)));
typedef unsigned int u32x4 __attribute__((ext_vector_type(4)));
typedef unsigned int u32x2 __attribute__((ext_vector_type(2)));

union H8 { u32x4 u; f16x8 h; };
union H4 { u32x2 u; f16 h[4]; };

// ---- LDS byte offsets (total 55296 <= 64KB) ----
#define ST(b)  ((b) * 8192)              // st[i][p] f16, i<32, p<128
#define STT(b) (24576 + (b) * 8192)      // st_T[p][j] f16, p<128, j<32
#define SC(b)  (49152 + (b) * 2048)      // scores S[i][j] f16, i<32, j<32
#define LDS_TOTAL 55296

__device__ __forceinline__ float exp2i(int e) {      // 2^e, e in [-126,127]
    return __uint_as_float((unsigned)(e + 127) << 23);
}
__device__ __forceinline__ int flog2(float m) {      // floor(log2 m), m>0 normal
    return (int)((__float_as_uint(m) >> 23) & 0xFF) - 127;
}

__global__ __launch_bounds__(256)
void agm_kernel(const float* __restrict__ x, const float* __restrict__ W_in,
                const float* __restrict__ b_in, const float* __restrict__ ns,
                const float* __restrict__ edge, const float* __restrict__ W_rec,
                const float* __restrict__ b_rec, const float* __restrict__ W_score,
                const float* __restrict__ b_score,
                float* __restrict__ out_rec, float* __restrict__ out_sc)
{
    __shared__ __align__(16) char smem[LDS_TOTAL];
    const int tid = threadIdx.x;
    const int w   = tid >> 6;          // wave 0..3; waves 0..2 own batches 0..2
    const int ln  = tid & 63;
    const int g   = ln >> 4;           // 0..3
    const int c15 = ln & 15;
    const long bg0 = (long)blockIdx.x * NBATCH;

    int sig = 0;                       // per-wave batch scale exponent

    // ---------------- Phase A (fp32 VALU, round-1 pattern) ----------------
    if (w < NBATCH) {
        long bgw = bg0 + w;
        if (bgw >= BTOT) bgw = BTOT - 1;          // clamp: compute, don't write
        const float* xb = x + bgw * 256;
        float a0 = b_in[ln], a1 = b_in[ln + 64];
        for (int k = 0; k < 256; k += 4) {
            const float4 xv = *(const float4*)(xb + k);
            a0 += xv.x * W_in[(k+0)*128 + ln];  a1 += xv.x * W_in[(k+0)*128 + 64 + ln];
            a0 += xv.y * W_in[(k+1)*128 + ln];  a1 += xv.y * W_in[(k+1)*128 + 64 + ln];
            a0 += xv.z * W_in[(k+2)*128 + ln];  a1 += xv.z * W_in[(k+2)*128 + 64 + ln];
            a0 += xv.w * W_in[(k+3)*128 + ln];  a1 += xv.w * W_in[(k+3)*128 + 64 + ln];
        }
        float v0[32], v1[32];
        float m = 1e-30f;
        #pragma unroll
        for (int i = 0; i < 32; ++i) {
            v0[i] = ns[i*128 + ln]      + a0;
            v1[i] = ns[i*128 + 64 + ln] + a1;
            m = fmaxf(m, fmaxf(fabsf(v0[i]), fabsf(v1[i])));
        }
        m = fmaxf(m, __shfl_xor(m, 1));
        m = fmaxf(m, __shfl_xor(m, 2));
        m = fmaxf(m, __shfl_xor(m, 4));
        m = fmaxf(m, __shfl_xor(m, 8));
        m = fmaxf(m, __shfl_xor(m, 16));
        m = fmaxf(m, __shfl_xor(m, 32));
        sig = 10 - flog2(m);                       // scaled max ~ 2^10
        const float s0 = exp2i(sig);
        #pragma unroll
        for (int i = 0; i < 32; ++i) {
            const f16 h0 = (f16)(v0[i] * s0);
            const f16 h1 = (f16)(v1[i] * s0);
            *(f16*)(smem + ST(w)  + (i*128 + ln) * 2)        = h0;
            *(f16*)(smem + ST(w)  + (i*128 + ln + 64) * 2)   = h1;
            *(f16*)(smem + STT(w) + (ln*32 + i) * 2)         = h0;
            *(f16*)(smem + STT(w) + ((ln + 64)*32 + i) * 2)  = h1;
        }
    }
    __syncthreads();

    // ---------------- 3 identical recurrence steps ----------------
    for (int t = 0; t < 3; ++t) {
        // ---- part1: S[i][j] (scaled) for all 3 batches.  D[m=j][n=batch] ----
        {
            const int bb = c15 < NBATCH ? c15 : NBATCH - 1;
            for (int ii = 0; ii < 8; ++ii) {
                const int i = w * 8 + ii;
                H8 Bf[4];
                #pragma unroll
                for (int ks = 0; ks < 4; ++ks)
                    Bf[ks].u = *(const u32x4*)(smem + ST(bb) + i*256 + ks*64 + g*16);
                f32x4 d0 = {0,0,0,0}, d1 = {0,0,0,0};
                #pragma unroll
                for (int ks = 0; ks < 4; ++ks) {
                    const float* e0 = edge + ((size_t)(i*32 + c15) * 128 + ks*32 + g*8);
                    const float* e1 = e0 + 2048;           // rows j+16
                    const float4 pa = *(const float4*)e0;
                    const float4 pb = *(const float4*)(e0 + 4);
                    const float4 qa = *(const float4*)e1;
                    const float4 qb = *(const float4*)(e1 + 4);
                    H8 A0, A1;
                    A0.h = (f16x8){(f16)pa.x,(f16)pa.y,(f16)pa.z,(f16)pa.w,
                                   (f16)pb.x,(f16)pb.y,(f16)pb.z,(f16)pb.w};
                    A1.h = (f16x8){(f16)qa.x,(f16)qa.y,(f16)qa.z,(f16)qa.w,
                                   (f16)qb.x,(f16)qb.y,(f16)qb.z,(f16)qb.w};
                    if (i == c15)      A0.u = (u32x4){0,0,0,0};   // off_diag j==i
                    if (i == 16 + c15) A1.u = (u32x4){0,0,0,0};
                    d0 = __builtin_amdgcn_mfma_f32_16x16x32_f16(A0.h, Bf[ks].h, d0, 0, 0, 0);
                    d1 = __builtin_amdgcn_mfma_f32_16x16x32_f16(A1.h, Bf[ks].h, d1, 0, 0, 0);
                }
                if (c15 < NBATCH) {                        // batch c15's scores
                    char* scb = smem + SC(c15) + i * 64;
                    H4 p0, p1;
                    #pragma unroll
                    for (int r = 0; r < 4; ++r) {
                        p0.h[r] = (f16)(d0[r] * 0x1p-8f);  // static safe scale 2^-8
                        p1.h[r] = (f16)(d1[r] * 0x1p-8f);
                    }
                    *(u32x2*)(scb + g*8)      = p0.u;      // j = g*4..g*4+3
                    *(u32x2*)(scb + 32 + g*8) = p1.u;      // j = 16+g*4..
                }
            }
        }
        __syncthreads();

        // ---- part2: wave w updates batch w.  D[m=i][n=p_local] ----
        if (w < NBATCH) {
            const char* scw = smem + SC(w);
            H8 alo, ahi;
            alo.u = *(const u32x4*)(scw + c15*64 + g*16);          // S[i=c15][j]
            ahi.u = *(const u32x4*)(scw + 1024 + c15*64 + g*16);   // S[i=16+c15][j]
            f32x4 dlo[8], dhi[8];
            #pragma unroll
            for (int pt = 0; pt < 8; ++pt) {
                H8 bf;   // B[k=j][n=p] = st_T[p=pt*16+c15][j = g*8..]
                bf.u = *(const u32x4*)(smem + STT(w) + (pt*16 + c15)*64 + g*16);
                const f32x4 z = {0,0,0,0};
                dlo[pt] = __builtin_amdgcn_mfma_f32_16x16x32_f16(alo.h, bf.h, z, 0, 0, 0);
                dhi[pt] = __builtin_amdgcn_mfma_f32_16x16x32_f16(ahi.h, bf.h, z, 0, 0, 0);
            }
            float mx = 0.f;
            #pragma unroll
            for (int pt = 0; pt < 8; ++pt)
                #pragma unroll
                for (int r = 0; r < 4; ++r)
                    mx = fmaxf(mx, fmaxf(dlo[pt][r], dhi[pt][r]));
            mx = fmaxf(mx, __shfl_xor(mx, 1));
            mx = fmaxf(mx, __shfl_xor(mx, 2));
            mx = fmaxf(mx, __shfl_xor(mx, 4));
            mx = fmaxf(mx, __shfl_xor(mx, 8));
            mx = fmaxf(mx, __shfl_xor(mx, 16));
            mx = fmaxf(mx, __shfl_xor(mx, 32));
            int ge = (mx > 1e-30f) ? (10 - flog2(mx)) : 0;
            if (ge > 60) ge = 60;
            if (ge < -60) ge = -60;
            sig = 2 * sig - 8 + ge;                  // new exponent chain
            const float gs = exp2i(ge);
            #pragma unroll
            for (int pt = 0; pt < 8; ++pt) {
                const int p = pt*16 + c15;
                #pragma unroll
                for (int r = 0; r < 4; ++r) {
                    const int il = g*4 + r, ih = il + 16;
                    const f16 vl = (f16)(fmaxf(dlo[pt][r], 0.f) * gs);
                    const f16 vh = (f16)(fmaxf(dhi[pt][r], 0.f) * gs);
                    *(f16*)(smem + ST(w)  + (il*128 + p) * 2) = vl;
                    *(f16*)(smem + STT(w) + (p*32 + il) * 2)  = vl;
                    *(f16*)(smem + ST(w)  + (ih*128 + p) * 2) = vh;
                    *(f16*)(smem + STT(w) + (p*32 + ih) * 2)  = vh;
                }
            }
        }
        __syncthreads();
    }

    // ---------------- Phase C: outputs (fp32 VALU, round-1 pattern) ----------------
    if (w < NBATCH) {
        const long bgw = bg0 + w;
        if (bgw < BTOT) {
            int e = -sig; if (e > 126) e = 126; if (e < -126) e = -126;
            const float dsc = exp2i(e);
            const char* strow = smem + ST(w) + 31*256;   // st[31][p] f16
            float r0 = 0.f, r1 = 0.f, r2 = 0.f, r3 = 0.f;
            for (int p = 0; p < 128; ++p) {
                const float ov = (float)(*(const f16*)(strow + p*2));
                r0 += ov * W_rec[p*256 + ln];
                r1 += ov * W_rec[p*256 + 64  + ln];
                r2 += ov * W_rec[p*256 + 128 + ln];
                r3 += ov * W_rec[p*256 + 192 + ln];
            }
            float* orow = out_rec + bgw * 256;
            orow[ln]       = r0 * dsc + b_rec[ln];
            orow[ln + 64]  = r1 * dsc + b_rec[ln + 64];
            orow[ln + 128] = r2 * dsc + b_rec[ln + 128];
            orow[ln + 192] = r3 * dsc + b_rec[ln + 192];

            const float o0 = (float)(*(const f16*)(strow + ln*2));
            const float o1 = (float)(*(const f16*)(strow + (ln + 64)*2));
            float v = o0 * W_score[ln] + o1 * W_score[ln + 64];
            v += __shfl_xor(v, 1);
            v += __shfl_xor(v, 2);
            v += __shfl_xor(v, 4);
            v += __shfl_xor(v, 8);
            v += __shfl_xor(v, 16);
            v += __shfl_xor(v, 32);
            if (ln == 0) out_sc[bgw] = v * dsc + b_score[0];
        }
    }
}

extern "C" void kernel_launch(void* const* d_in, const int* in_sizes, int n_in,
                              void* d_out, int out_size, void* d_ws, size_t ws_size,
                              hipStream_t stream) {
    const float* x     = (const float*)d_in[0];
    const float* W_in  = (const float*)d_in[1];
    const float* bin   = (const float*)d_in[2];
    const float* ns    = (const float*)d_in[3];
    const float* edge  = (const float*)d_in[4];
    const float* W_rec = (const float*)d_in[5];
    const float* brec  = (const float*)d_in[6];
    const float* W_sc  = (const float*)d_in[7];
    const float* b_sc  = (const float*)d_in[8];
    (void)d_ws; (void)ws_size; (void)n_in;

    const int B = in_sizes[0] / 256;               // 16384
    float* out = (float*)d_out;
    float* outsc = out + (size_t)B * 256;

    const int nblk = (B + NBATCH - 1) / NBATCH;    // 5462
    agm_kernel<<<dim3(nblk), dim3(256), 0, stream>>>(
        x, W_in, bin, ns, edge, W_rec, brec, W_sc, b_sc, out, outsc);
}

// Round 6
// 540.940 us; speedup vs baseline: 3.0403x; 2.1214x over previous
//
#include <hip/hip_runtime.h>
#include <cstdint>

// AGMBrain: B=16384, INPUT_DIM=256, N=32 neurons, D=128, 3 steps.
// Round 6: single-kernel fp16 MFMA, NBATCH=6, single-layout states + scalar
// transpose reads in part2, step-3 row-31 specialization.
//   - proven envelope: 256 threads, 64.6KB... (64608B <= 65536) static LDS,
//     no ws, no inline asm, no tr-reads.
//   - states: ST(b) + i*272 + q*2 (row pad 16B, batch pad 16B: part1 6-batch
//     B-reads land on disjoint bank groups; 272 is 16B-aligned for b128).
//   - part1 (t<2): D[j][b] = sum_q E[i][j][q]*st[b][i][q]; A=edge fp32->f16
//     in-reg, B=st rows (b128), 6 batch columns per MFMA.
//   - part2 (t<2): D[i][p] = sum_j S[i][j]*st[j][p]; A=S rows (b128), B via
//     64 ds_read_u16 per batch (transpose reads), wave w owns batches {w,w+4}.
//   - t==2: part1 only i=31 (wave 3); part2 only hi tile, store row 31.
//   - per-batch power-of-2 scaling in registers, descaled in fp32 epilogue.

#define BTOT 16384
#define NBATCH 6
#define ROWB 272                 // bytes per state row (128 f16 + 8 pad)
#define STB  8720                // bytes per batch (32*272 + 16 pad)
#define ST(b) ((b) * STB)
#define SC_BASE 52320            // 6*8720
#define SC(b) (SC_BASE + (b) * 2048)   // scores S[i][j] f16, 64B/row
#define LDS_TOTAL 64608          // 52320 + 6*2048

typedef _Float16 f16;
typedef _Float16 f16x8 __attribute__((ext_vector_type(8)));
typedef float f32x4 __attribute__((ext_vector_type(4)));
typedef unsigned int u32x4 __attribute__((ext_vector_type(4)));
typedef unsigned int u32x2 __attribute__((ext_vector_type(2)));

union H8 { u32x4 u; f16x8 h; };
union H4 { u32x2 u; f16 h[4]; };

__device__ __forceinline__ float exp2i(int e) {      // 2^e, e in [-126,127]
    return __uint_as_float((unsigned)(e + 127) << 23);
}
__device__ __forceinline__ int flog2(float m) {      // floor(log2 m), m>0 normal
    return (int)((__float_as_uint(m) >> 23) & 0xFF) - 127;
}

__global__ __launch_bounds__(256)
void agm_kernel(const float* __restrict__ x, const float* __restrict__ W_in,
                const float* __restrict__ b_in, const float* __restrict__ ns,
                const float* __restrict__ edge, const float* __restrict__ W_rec,
                const float* __restrict__ b_rec, const float* __restrict__ W_score,
                const float* __restrict__ b_score,
                float* __restrict__ out_rec, float* __restrict__ out_sc)
{
    __shared__ __align__(16) char smem[LDS_TOTAL];
    const int tid = threadIdx.x;
    const int w   = tid >> 6;          // wave 0..3; wave w owns batches {w, w+4}
    const int ln  = tid & 63;
    const int g   = ln >> 4;           // 0..3
    const int c15 = ln & 15;
    const long bg0 = (long)blockIdx.x * NBATCH;

    int sig[2] = {0, 0};               // scale exponents for batches w, w+4

    // ---------------- Phase A: x_t = x@W_in + b_in ; st0 = ns + x_t ----------------
    #pragma unroll
    for (int s = 0; s < 2; ++s) {
        const int bb = w + 4 * s;
        if (bb < NBATCH) {
            long bgw = bg0 + bb;
            if (bgw >= BTOT) bgw = BTOT - 1;       // clamp: compute, don't store
            const float* xb = x + bgw * 256;
            float a0 = b_in[ln], a1 = b_in[ln + 64];
            for (int k = 0; k < 256; k += 4) {
                const float4 xv = *(const float4*)(xb + k);
                a0 += xv.x * W_in[(k+0)*128 + ln];  a1 += xv.x * W_in[(k+0)*128 + 64 + ln];
                a0 += xv.y * W_in[(k+1)*128 + ln];  a1 += xv.y * W_in[(k+1)*128 + 64 + ln];
                a0 += xv.z * W_in[(k+2)*128 + ln];  a1 += xv.z * W_in[(k+2)*128 + 64 + ln];
                a0 += xv.w * W_in[(k+3)*128 + ln];  a1 += xv.w * W_in[(k+3)*128 + 64 + ln];
            }
            float v0[32], v1[32];
            float m = 1e-30f;
            #pragma unroll
            for (int i = 0; i < 32; ++i) {
                v0[i] = ns[i*128 + ln]      + a0;
                v1[i] = ns[i*128 + 64 + ln] + a1;
                m = fmaxf(m, fmaxf(fabsf(v0[i]), fabsf(v1[i])));
            }
            m = fmaxf(m, __shfl_xor(m, 1));
            m = fmaxf(m, __shfl_xor(m, 2));
            m = fmaxf(m, __shfl_xor(m, 4));
            m = fmaxf(m, __shfl_xor(m, 8));
            m = fmaxf(m, __shfl_xor(m, 16));
            m = fmaxf(m, __shfl_xor(m, 32));
            sig[s] = 10 - flog2(m);                // scaled max ~ 2^10
            const float s0 = exp2i(sig[s]);
            #pragma unroll
            for (int i = 0; i < 32; ++i) {
                *(f16*)(smem + ST(bb) + i*ROWB + ln*2)        = (f16)(v0[i] * s0);
                *(f16*)(smem + ST(bb) + i*ROWB + (ln + 64)*2) = (f16)(v1[i] * s0);
            }
        }
    }
    __syncthreads();

    // ---------------- 3 recurrence steps ----------------
    for (int t = 0; t < 3; ++t) {
        // ---- part1: S[i][j] for all 6 batches.  D[m=j][n=batch] per i ----
        if (t < 2) {
            const int bb = c15 < NBATCH ? c15 : NBATCH - 1;
            for (int ii = 0; ii < 8; ++ii) {
                const int i = w * 8 + ii;
                H8 Bf[4];
                #pragma unroll
                for (int ks = 0; ks < 4; ++ks)
                    Bf[ks].u = *(const u32x4*)(smem + ST(bb) + i*ROWB + (ks*32 + g*8)*2);
                f32x4 d0 = {0,0,0,0}, d1 = {0,0,0,0};
                #pragma unroll
                for (int ks = 0; ks < 4; ++ks) {
                    const float* e0 = edge + ((size_t)(i*32 + c15) * 128 + ks*32 + g*8);
                    const float* e1 = e0 + 2048;           // rows j+16
                    const float4 pa = *(const float4*)e0;
                    const float4 pb = *(const float4*)(e0 + 4);
                    const float4 qa = *(const float4*)e1;
                    const float4 qb = *(const float4*)(e1 + 4);
                    H8 A0, A1;
                    A0.h = (f16x8){(f16)pa.x,(f16)pa.y,(f16)pa.z,(f16)pa.w,
                                   (f16)pb.x,(f16)pb.y,(f16)pb.z,(f16)pb.w};
                    A1.h = (f16x8){(f16)qa.x,(f16)qa.y,(f16)qa.z,(f16)qa.w,
                                   (f16)qb.x,(f16)qb.y,(f16)qb.z,(f16)qb.w};
                    if (i == c15)      A0.u = (u32x4){0,0,0,0};   // off_diag j==i
                    if (i == 16 + c15) A1.u = (u32x4){0,0,0,0};
                    d0 = __builtin_amdgcn_mfma_f32_16x16x32_f16(A0.h, Bf[ks].h, d0, 0, 0, 0);
                    d1 = __builtin_amdgcn_mfma_f32_16x16x32_f16(A1.h, Bf[ks].h, d1, 0, 0, 0);
                }
                if (c15 < NBATCH) {
                    char* scb = smem + SC(c15) + i * 64;
                    H4 p0, p1;
                    #pragma unroll
                    for (int r = 0; r < 4; ++r) {
                        p0.h[r] = (f16)(d0[r] * 0x1p-8f);  // static safe scale 2^-8
                        p1.h[r] = (f16)(d1[r] * 0x1p-8f);
                    }
                    *(u32x2*)(scb + g*8)      = p0.u;      // j = g*4..g*4+3
                    *(u32x2*)(scb + 32 + g*8) = p1.u;      // j = 16+g*4..
                }
            }
        } else if (w == 3) {                               // step 3: only i = 31
            const int i = 31;
            const int bb = c15 < NBATCH ? c15 : NBATCH - 1;
            H8 Bf[4];
            #pragma unroll
            for (int ks = 0; ks < 4; ++ks)
                Bf[ks].u = *(const u32x4*)(smem + ST(bb) + i*ROWB + (ks*32 + g*8)*2);
            f32x4 d0 = {0,0,0,0}, d1 = {0,0,0,0};
            #pragma unroll
            for (int ks = 0; ks < 4; ++ks) {
                const float* e0 = edge + ((size_t)(i*32 + c15) * 128 + ks*32 + g*8);
                const float* e1 = e0 + 2048;
                const float4 pa = *(const float4*)e0;
                const float4 pb = *(const float4*)(e0 + 4);
                const float4 qa = *(const float4*)e1;
                const float4 qb = *(const float4*)(e1 + 4);
                H8 A0, A1;
                A0.h = (f16x8){(f16)pa.x,(f16)pa.y,(f16)pa.z,(f16)pa.w,
                               (f16)pb.x,(f16)pb.y,(f16)pb.z,(f16)pb.w};
                A1.h = (f16x8){(f16)qa.x,(f16)qa.y,(f16)qa.z,(f16)qa.w,
                               (f16)qb.x,(f16)qb.y,(f16)qb.z,(f16)qb.w};
                if (i == 16 + c15) A1.u = (u32x4){0,0,0,0};       // j==31
                d0 = __builtin_amdgcn_mfma_f32_16x16x32_f16(A0.h, Bf[ks].h, d0, 0, 0, 0);
                d1 = __builtin_amdgcn_mfma_f32_16x16x32_f16(A1.h, Bf[ks].h, d1, 0, 0, 0);
            }
            if (c15 < NBATCH) {
                char* scb = smem + SC(c15) + i * 64;
                H4 p0, p1;
                #pragma unroll
                for (int r = 0; r < 4; ++r) {
                    p0.h[r] = (f16)(d0[r] * 0x1p-8f);
                    p1.h[r] = (f16)(d1[r] * 0x1p-8f);
                }
                *(u32x2*)(scb + g*8)      = p0.u;
                *(u32x2*)(scb + 32 + g*8) = p1.u;
            }
        }
        __syncthreads();

        // ---- part2: wave w updates batches {w, w+4}.  D[m=i][n=p] ----
        #pragma unroll
        for (int s = 0; s < 2; ++s) {
            const int bb = w + 4 * s;
            if (bb >= NBATCH) continue;
            const char* scb = smem + SC(bb);
            if (t < 2) {
                H8 alo, ahi;
                alo.u = *(const u32x4*)(scb + c15*64 + g*16);          // S[i=c15][j]
                ahi.u = *(const u32x4*)(scb + 1024 + c15*64 + g*16);   // S[i=16+c15][j]
                f32x4 dlo[8], dhi[8];
                #pragma unroll
                for (int pt = 0; pt < 8; ++pt) {
                    H8 bf;   // B[k=j][n=p]: st[j = g*8+jj][p = pt*16+c15]
                    #pragma unroll
                    for (int jj = 0; jj < 8; ++jj)
                        bf.h[jj] = *(const f16*)(smem + ST(bb) + (g*8 + jj)*ROWB
                                                 + (pt*16 + c15)*2);
                    const f32x4 z = {0,0,0,0};
                    dlo[pt] = __builtin_amdgcn_mfma_f32_16x16x32_f16(alo.h, bf.h, z, 0, 0, 0);
                    dhi[pt] = __builtin_amdgcn_mfma_f32_16x16x32_f16(ahi.h, bf.h, z, 0, 0, 0);
                }
                float mx = 0.f;
                #pragma unroll
                for (int pt = 0; pt < 8; ++pt)
                    #pragma unroll
                    for (int r = 0; r < 4; ++r)
                        mx = fmaxf(mx, fmaxf(dlo[pt][r], dhi[pt][r]));
                mx = fmaxf(mx, __shfl_xor(mx, 1));
                mx = fmaxf(mx, __shfl_xor(mx, 2));
                mx = fmaxf(mx, __shfl_xor(mx, 4));
                mx = fmaxf(mx, __shfl_xor(mx, 8));
                mx = fmaxf(mx, __shfl_xor(mx, 16));
                mx = fmaxf(mx, __shfl_xor(mx, 32));
                int ge = (mx > 1e-30f) ? (10 - flog2(mx)) : 0;
                if (ge > 60) ge = 60;
                if (ge < -60) ge = -60;
                sig[s] = 2 * sig[s] - 8 + ge;
                const float gs = exp2i(ge);
                #pragma unroll
                for (int pt = 0; pt < 8; ++pt) {
                    const int p = pt*16 + c15;
                    #pragma unroll
                    for (int r = 0; r < 4; ++r) {
                        const int il = g*4 + r, ih = il + 16;
                        *(f16*)(smem + ST(bb) + il*ROWB + p*2) =
                            (f16)(fmaxf(dlo[pt][r], 0.f) * gs);
                        *(f16*)(smem + ST(bb) + ih*ROWB + p*2) =
                            (f16)(fmaxf(dhi[pt][r], 0.f) * gs);
                    }
                }
            } else {    // step 3: only hi i-tile; keep only row 31
                H8 ahi;
                ahi.u = *(const u32x4*)(scb + 1024 + c15*64 + g*16);
                f32x4 dhi[8];
                #pragma unroll
                for (int pt = 0; pt < 8; ++pt) {
                    H8 bf;
                    #pragma unroll
                    for (int jj = 0; jj < 8; ++jj)
                        bf.h[jj] = *(const f16*)(smem + ST(bb) + (g*8 + jj)*ROWB
                                                 + (pt*16 + c15)*2);
                    const f32x4 z = {0,0,0,0};
                    dhi[pt] = __builtin_amdgcn_mfma_f32_16x16x32_f16(ahi.h, bf.h, z, 0, 0, 0);
                }
                float mx = 0.f;
                if (g == 3) {                  // lane rows (l>>4)*4+r: row 31 = g3,r3
                    #pragma unroll
                    for (int pt = 0; pt < 8; ++pt) mx = fmaxf(mx, dhi[pt][3]);
                }
                mx = fmaxf(mx, __shfl_xor(mx, 1));
                mx = fmaxf(mx, __shfl_xor(mx, 2));
                mx = fmaxf(mx, __shfl_xor(mx, 4));
                mx = fmaxf(mx, __shfl_xor(mx, 8));
                mx = fmaxf(mx, __shfl_xor(mx, 16));
                mx = fmaxf(mx, __shfl_xor(mx, 32));
                int ge = (mx > 1e-30f) ? (10 - flog2(mx)) : 0;
                if (ge > 60) ge = 60;
                if (ge < -60) ge = -60;
                sig[s] = 2 * sig[s] - 8 + ge;
                const float gs = exp2i(ge);
                if (g == 3) {
                    #pragma unroll
                    for (int pt = 0; pt < 8; ++pt)
                        *(f16*)(smem + ST(bb) + 31*ROWB + (pt*16 + c15)*2) =
                            (f16)(fmaxf(dhi[pt][3], 0.f) * gs);
                }
            }
        }
        __syncthreads();
    }

    // ---------------- Phase C: outputs ----------------
    #pragma unroll
    for (int s = 0; s < 2; ++s) {
        const int bb = w + 4 * s;
        if (bb >= NBATCH) continue;
        const long bgw = bg0 + bb;
        if (bgw >= BTOT) continue;
        int e = -sig[s]; if (e > 126) e = 126; if (e < -126) e = -126;
        const float dsc = exp2i(e);
        const char* strow = smem + ST(bb) + 31*ROWB;       // st[31][p] f16
        float r0 = 0.f, r1 = 0.f, r2 = 0.f, r3 = 0.f;
        for (int p = 0; p < 128; ++p) {
            const float ov = (float)(*(const f16*)(strow + p*2));
            r0 += ov * W_rec[p*256 + ln];
            r1 += ov * W_rec[p*256 + 64  + ln];
            r2 += ov * W_rec[p*256 + 128 + ln];
            r3 += ov * W_rec[p*256 + 192 + ln];
        }
        float* orow = out_rec + bgw * 256;
        orow[ln]       = r0 * dsc + b_rec[ln];
        orow[ln + 64]  = r1 * dsc + b_rec[ln + 64];
        orow[ln + 128] = r2 * dsc + b_rec[ln + 128];
        orow[ln + 192] = r3 * dsc + b_rec[ln + 192];

        const float o0 = (float)(*(const f16*)(strow + ln*2));
        const float o1 = (float)(*(const f16*)(strow + (ln + 64)*2));
        float v = o0 * W_score[ln] + o1 * W_score[ln + 64];
        v += __shfl_xor(v, 1);
        v += __shfl_xor(v, 2);
        v += __shfl_xor(v, 4);
        v += __shfl_xor(v, 8);
        v += __shfl_xor(v, 16);
        v += __shfl_xor(v, 32);
        if (ln == 0) out_sc[bgw] = v * dsc + b_score[0];
    }
}

extern "C" void kernel_launch(void* const* d_in, const int* in_sizes, int n_in,
                              void* d_out, int out_size, void* d_ws, size_t ws_size,
                              hipStream_t stream) {
    const float* x     = (const float*)d_in[0];
    const float* W_in  = (const float*)d_in[1];
    const float* bin   = (const float*)d_in[2];
    const float* ns    = (const float*)d_in[3];
    const float* edge  = (const float*)d_in[4];
    const float* W_rec = (const float*)d_in[5];
    const float* brec  = (const float*)d_in[6];
    const float* W_sc  = (const float*)d_in[7];
    const float* b_sc  = (const float*)d_in[8];
    (void)d_ws; (void)ws_size; (void)n_in;

    const int B = in_sizes[0] / 256;               // 16384
    float* out = (float*)d_out;
    float* outsc = out + (size_t)B * 256;

    const int nblk = (B + NBATCH - 1) / NBATCH;    // 2731
    agm_kernel<<<dim3(nblk), dim3(256), 0, stream>>>(
        x, W_in, bin, ns, edge, W_rec, brec, W_sc, b_sc, out, outsc);
}

// Round 7
// 529.127 us; speedup vs baseline: 3.1082x; 1.0223x over previous
//
#include <hip/hip_runtime.h>
#include <cstdint>

// AGMBrain: B=16384, INPUT_DIM=256, N=32 neurons, D=128, 3 steps.
// Round 7: r6 numerics/layout, re-parallelized onto 512 threads (8 waves).
//   - Phase A / part2 / Phase C: 1 batch per wave (waves 0..5), was 2 per wave.
//   - part1: 4 i-rows per wave (waves 0..7), was 8; t==2 row 31 -> wave 7.
//   - __launch_bounds__(512,4): 4 waves/SIMD, 16 waves/CU (2 blocks/CU by LDS).
//   - LDS layout identical to r6 (ST stride 8720 -> 6 distinct bank groups
//     across batch reads; ROWB=272 kills row-stride conflicts). 64608 B.
//   - per-batch power-of-2 scaling in registers; descaled fp32 epilogue.
//   - absmax must match r6 exactly (2.199e12) -- numerics unchanged.

#define BTOT 16384
#define NBATCH 6
#define ROWB 272                 // bytes per state row (128 f16 + 8 pad)
#define STB  8720                // bytes per batch (32*272 + 16 pad)
#define ST(b) ((b) * STB)
#define SC_BASE 52320            // 6*8720
#define SC(b) (SC_BASE + (b) * 2048)   // scores S[i][j] f16, 64B/row
#define LDS_TOTAL 64608          // 52320 + 6*2048

typedef _Float16 f16;
typedef _Float16 f16x8 __attribute__((ext_vector_type(8)));
typedef float f32x4 __attribute__((ext_vector_type(4)));
typedef unsigned int u32x4 __attribute__((ext_vector_type(4)));
typedef unsigned int u32x2 __attribute__((ext_vector_type(2)));

union H8 { u32x4 u; f16x8 h; };
union H4 { u32x2 u; f16 h[4]; };

__device__ __forceinline__ float exp2i(int e) {      // 2^e, e in [-126,127]
    return __uint_as_float((unsigned)(e + 127) << 23);
}
__device__ __forceinline__ int flog2(float m) {      // floor(log2 m), m>0 normal
    return (int)((__float_as_uint(m) >> 23) & 0xFF) - 127;
}

__global__ __launch_bounds__(512, 4)
void agm_kernel(const float* __restrict__ x, const float* __restrict__ W_in,
                const float* __restrict__ b_in, const float* __restrict__ ns,
                const float* __restrict__ edge, const float* __restrict__ W_rec,
                const float* __restrict__ b_rec, const float* __restrict__ W_score,
                const float* __restrict__ b_score,
                float* __restrict__ out_rec, float* __restrict__ out_sc)
{
    __shared__ __align__(16) char smem[LDS_TOTAL];
    const int tid = threadIdx.x;
    const int w   = tid >> 6;          // wave 0..7; wave w<6 owns batch w
    const int ln  = tid & 63;
    const int g   = ln >> 4;           // 0..3
    const int c15 = ln & 15;
    const long bg0 = (long)blockIdx.x * NBATCH;

    int sig = 0;                       // scale exponent for batch w

    // ---------------- Phase A: x_t = x@W_in + b_in ; st0 = ns + x_t ----------------
    if (w < NBATCH) {
        long bgw = bg0 + w;
        if (bgw >= BTOT) bgw = BTOT - 1;           // clamp: compute, don't store out
        const float* xb = x + bgw * 256;
        float a0 = b_in[ln], a1 = b_in[ln + 64];
        for (int k = 0; k < 256; k += 4) {
            const float4 xv = *(const float4*)(xb + k);
            a0 += xv.x * W_in[(k+0)*128 + ln];  a1 += xv.x * W_in[(k+0)*128 + 64 + ln];
            a0 += xv.y * W_in[(k+1)*128 + ln];  a1 += xv.y * W_in[(k+1)*128 + 64 + ln];
            a0 += xv.z * W_in[(k+2)*128 + ln];  a1 += xv.z * W_in[(k+2)*128 + 64 + ln];
            a0 += xv.w * W_in[(k+3)*128 + ln];  a1 += xv.w * W_in[(k+3)*128 + 64 + ln];
        }
        float v0[32], v1[32];
        float m = 1e-30f;
        #pragma unroll
        for (int i = 0; i < 32; ++i) {
            v0[i] = ns[i*128 + ln]      + a0;
            v1[i] = ns[i*128 + 64 + ln] + a1;
            m = fmaxf(m, fmaxf(fabsf(v0[i]), fabsf(v1[i])));
        }
        m = fmaxf(m, __shfl_xor(m, 1));
        m = fmaxf(m, __shfl_xor(m, 2));
        m = fmaxf(m, __shfl_xor(m, 4));
        m = fmaxf(m, __shfl_xor(m, 8));
        m = fmaxf(m, __shfl_xor(m, 16));
        m = fmaxf(m, __shfl_xor(m, 32));
        sig = 10 - flog2(m);                       // scaled max ~ 2^10
        const float s0 = exp2i(sig);
        #pragma unroll
        for (int i = 0; i < 32; ++i) {
            *(f16*)(smem + ST(w) + i*ROWB + ln*2)        = (f16)(v0[i] * s0);
            *(f16*)(smem + ST(w) + i*ROWB + (ln + 64)*2) = (f16)(v1[i] * s0);
        }
    }
    __syncthreads();

    // ---------------- 3 recurrence steps ----------------
    for (int t = 0; t < 3; ++t) {
        // ---- part1: S[i][j] for all 6 batches.  D[m=j][n=batch] per i ----
        if (t < 2) {
            const int bb = c15 < NBATCH ? c15 : NBATCH - 1;
            for (int ii = 0; ii < 4; ++ii) {
                const int i = w * 4 + ii;
                H8 Bf[4];
                #pragma unroll
                for (int ks = 0; ks < 4; ++ks)
                    Bf[ks].u = *(const u32x4*)(smem + ST(bb) + i*ROWB + (ks*32 + g*8)*2);
                f32x4 d0 = {0,0,0,0}, d1 = {0,0,0,0};
                #pragma unroll
                for (int ks = 0; ks < 4; ++ks) {
                    const float* e0 = edge + ((size_t)(i*32 + c15) * 128 + ks*32 + g*8);
                    const float* e1 = e0 + 2048;           // rows j+16
                    const float4 pa = *(const float4*)e0;
                    const float4 pb = *(const float4*)(e0 + 4);
                    const float4 qa = *(const float4*)e1;
                    const float4 qb = *(const float4*)(e1 + 4);
                    H8 A0, A1;
                    A0.h = (f16x8){(f16)pa.x,(f16)pa.y,(f16)pa.z,(f16)pa.w,
                                   (f16)pb.x,(f16)pb.y,(f16)pb.z,(f16)pb.w};
                    A1.h = (f16x8){(f16)qa.x,(f16)qa.y,(f16)qa.z,(f16)qa.w,
                                   (f16)qb.x,(f16)qb.y,(f16)qb.z,(f16)qb.w};
                    if (i == c15)      A0.u = (u32x4){0,0,0,0};   // off_diag j==i
                    if (i == 16 + c15) A1.u = (u32x4){0,0,0,0};
                    d0 = __builtin_amdgcn_mfma_f32_16x16x32_f16(A0.h, Bf[ks].h, d0, 0, 0, 0);
                    d1 = __builtin_amdgcn_mfma_f32_16x16x32_f16(A1.h, Bf[ks].h, d1, 0, 0, 0);
                }
                if (c15 < NBATCH) {
                    char* scb = smem + SC(c15) + i * 64;
                    H4 p0, p1;
                    #pragma unroll
                    for (int r = 0; r < 4; ++r) {
                        p0.h[r] = (f16)(d0[r] * 0x1p-8f);  // static safe scale 2^-8
                        p1.h[r] = (f16)(d1[r] * 0x1p-8f);
                    }
                    *(u32x2*)(scb + g*8)      = p0.u;      // j = g*4..g*4+3
                    *(u32x2*)(scb + 32 + g*8) = p1.u;      // j = 16+g*4..
                }
            }
        } else if (w == 7) {                               // step 3: only i = 31
            const int i = 31;
            const int bb = c15 < NBATCH ? c15 : NBATCH - 1;
            H8 Bf[4];
            #pragma unroll
            for (int ks = 0; ks < 4; ++ks)
                Bf[ks].u = *(const u32x4*)(smem + ST(bb) + i*ROWB + (ks*32 + g*8)*2);
            f32x4 d0 = {0,0,0,0}, d1 = {0,0,0,0};
            #pragma unroll
            for (int ks = 0; ks < 4; ++ks) {
                const float* e0 = edge + ((size_t)(i*32 + c15) * 128 + ks*32 + g*8);
                const float* e1 = e0 + 2048;
                const float4 pa = *(const float4*)e0;
                const float4 pb = *(const float4*)(e0 + 4);
                const float4 qa = *(const float4*)e1;
                const float4 qb = *(const float4*)(e1 + 4);
                H8 A0, A1;
                A0.h = (f16x8){(f16)pa.x,(f16)pa.y,(f16)pa.z,(f16)pa.w,
                               (f16)pb.x,(f16)pb.y,(f16)pb.z,(f16)pb.w};
                A1.h = (f16x8){(f16)qa.x,(f16)qa.y,(f16)qa.z,(f16)qa.w,
                               (f16)qb.x,(f16)qb.y,(f16)qb.z,(f16)qb.w};
                if (i == 16 + c15) A1.u = (u32x4){0,0,0,0};       // j==31
                d0 = __builtin_amdgcn_mfma_f32_16x16x32_f16(A0.h, Bf[ks].h, d0, 0, 0, 0);
                d1 = __builtin_amdgcn_mfma_f32_16x16x32_f16(A1.h, Bf[ks].h, d1, 0, 0, 0);
            }
            if (c15 < NBATCH) {
                char* scb = smem + SC(c15) + i * 64;
                H4 p0, p1;
                #pragma unroll
                for (int r = 0; r < 4; ++r) {
                    p0.h[r] = (f16)(d0[r] * 0x1p-8f);
                    p1.h[r] = (f16)(d1[r] * 0x1p-8f);
                }
                *(u32x2*)(scb + g*8)      = p0.u;
                *(u32x2*)(scb + 32 + g*8) = p1.u;
            }
        }
        __syncthreads();

        // ---- part2: wave w updates batch w.  D[m=i][n=p] ----
        if (w < NBATCH) {
            const int bb = w;
            const char* scb = smem + SC(bb);
            if (t < 2) {
                H8 alo, ahi;
                alo.u = *(const u32x4*)(scb + c15*64 + g*16);          // S[i=c15][j]
                ahi.u = *(const u32x4*)(scb + 1024 + c15*64 + g*16);   // S[i=16+c15][j]
                f32x4 dlo[8], dhi[8];
                #pragma unroll
                for (int pt = 0; pt < 8; ++pt) {
                    H8 bf;   // B[k=j][n=p]: st[j = g*8+jj][p = pt*16+c15]
                    #pragma unroll
                    for (int jj = 0; jj < 8; ++jj)
                        bf.h[jj] = *(const f16*)(smem + ST(bb) + (g*8 + jj)*ROWB
                                                 + (pt*16 + c15)*2);
                    const f32x4 z = {0,0,0,0};
                    dlo[pt] = __builtin_amdgcn_mfma_f32_16x16x32_f16(alo.h, bf.h, z, 0, 0, 0);
                    dhi[pt] = __builtin_amdgcn_mfma_f32_16x16x32_f16(ahi.h, bf.h, z, 0, 0, 0);
                }
                float mx = 0.f;
                #pragma unroll
                for (int pt = 0; pt < 8; ++pt)
                    #pragma unroll
                    for (int r = 0; r < 4; ++r)
                        mx = fmaxf(mx, fmaxf(dlo[pt][r], dhi[pt][r]));
                mx = fmaxf(mx, __shfl_xor(mx, 1));
                mx = fmaxf(mx, __shfl_xor(mx, 2));
                mx = fmaxf(mx, __shfl_xor(mx, 4));
                mx = fmaxf(mx, __shfl_xor(mx, 8));
                mx = fmaxf(mx, __shfl_xor(mx, 16));
                mx = fmaxf(mx, __shfl_xor(mx, 32));
                int ge = (mx > 1e-30f) ? (10 - flog2(mx)) : 0;
                if (ge > 60) ge = 60;
                if (ge < -60) ge = -60;
                sig = 2 * sig - 8 + ge;
                const float gs = exp2i(ge);
                #pragma unroll
                for (int pt = 0; pt < 8; ++pt) {
                    const int p = pt*16 + c15;
                    #pragma unroll
                    for (int r = 0; r < 4; ++r) {
                        const int il = g*4 + r, ih = il + 16;
                        *(f16*)(smem + ST(bb) + il*ROWB + p*2) =
                            (f16)(fmaxf(dlo[pt][r], 0.f) * gs);
                        *(f16*)(smem + ST(bb) + ih*ROWB + p*2) =
                            (f16)(fmaxf(dhi[pt][r], 0.f) * gs);
                    }
                }
            } else {    // step 3: only hi i-tile; keep only row 31
                H8 ahi;
                ahi.u = *(const u32x4*)(scb + 1024 + c15*64 + g*16);
                f32x4 dhi[8];
                #pragma unroll
                for (int pt = 0; pt < 8; ++pt) {
                    H8 bf;
                    #pragma unroll
                    for (int jj = 0; jj < 8; ++jj)
                        bf.h[jj] = *(const f16*)(smem + ST(bb) + (g*8 + jj)*ROWB
                                                 + (pt*16 + c15)*2);
                    const f32x4 z = {0,0,0,0};
                    dhi[pt] = __builtin_amdgcn_mfma_f32_16x16x32_f16(ahi.h, bf.h, z, 0, 0, 0);
                }
                float mx = 0.f;
                if (g == 3) {                  // D rows (l>>4)*4+r: row 31 = g3,r3
                    #pragma unroll
                    for (int pt = 0; pt < 8; ++pt) mx = fmaxf(mx, dhi[pt][3]);
                }
                mx = fmaxf(mx, __shfl_xor(mx, 1));
                mx = fmaxf(mx, __shfl_xor(mx, 2));
                mx = fmaxf(mx, __shfl_xor(mx, 4));
                mx = fmaxf(mx, __shfl_xor(mx, 8));
                mx = fmaxf(mx, __shfl_xor(mx, 16));
                mx = fmaxf(mx, __shfl_xor(mx, 32));
                int ge = (mx > 1e-30f) ? (10 - flog2(mx)) : 0;
                if (ge > 60) ge = 60;
                if (ge < -60) ge = -60;
                sig = 2 * sig - 8 + ge;
                const float gs = exp2i(ge);
                if (g == 3) {
                    #pragma unroll
                    for (int pt = 0; pt < 8; ++pt)
                        *(f16*)(smem + ST(bb) + 31*ROWB + (pt*16 + c15)*2) =
                            (f16)(fmaxf(dhi[pt][3], 0.f) * gs);
                }
            }
        }
        __syncthreads();
    }

    // ---------------- Phase C: outputs ----------------
    if (w < NBATCH) {
        const long bgw = bg0 + w;
        if (bgw < BTOT) {
            int e = -sig; if (e > 126) e = 126; if (e < -126) e = -126;
            const float dsc = exp2i(e);
            const char* strow = smem + ST(w) + 31*ROWB;    // st[31][p] f16
            float r0 = 0.f, r1 = 0.f, r2 = 0.f, r3 = 0.f;
            for (int p = 0; p < 128; ++p) {
                const float ov = (float)(*(const f16*)(strow + p*2));
                r0 += ov * W_rec[p*256 + ln];
                r1 += ov * W_rec[p*256 + 64  + ln];
                r2 += ov * W_rec[p*256 + 128 + ln];
                r3 += ov * W_rec[p*256 + 192 + ln];
            }
            float* orow = out_rec + bgw * 256;
            orow[ln]       = r0 * dsc + b_rec[ln];
            orow[ln + 64]  = r1 * dsc + b_rec[ln + 64];
            orow[ln + 128] = r2 * dsc + b_rec[ln + 128];
            orow[ln + 192] = r3 * dsc + b_rec[ln + 192];

            const float o0 = (float)(*(const f16*)(strow + ln*2));
            const float o1 = (float)(*(const f16*)(strow + (ln + 64)*2));
            float v = o0 * W_score[ln] + o1 * W_score[ln + 64];
            v += __shfl_xor(v, 1);
            v += __shfl_xor(v, 2);
            v += __shfl_xor(v, 4);
            v += __shfl_xor(v, 8);
            v += __shfl_xor(v, 16);
            v += __shfl_xor(v, 32);
            if (ln == 0) out_sc[bgw] = v * dsc + b_score[0];
        }
    }
}

extern "C" void kernel_launch(void* const* d_in, const int* in_sizes, int n_in,
                              void* d_out, int out_size, void* d_ws, size_t ws_size,
                              hipStream_t stream) {
    const float* x     = (const float*)d_in[0];
    const float* W_in  = (const float*)d_in[1];
    const float* bin   = (const float*)d_in[2];
    const float* ns    = (const float*)d_in[3];
    const float* edge  = (const float*)d_in[4];
    const float* W_rec = (const float*)d_in[5];
    const float* brec  = (const float*)d_in[6];
    const float* W_sc  = (const float*)d_in[7];
    const float* b_sc  = (const float*)d_in[8];
    (void)d_ws; (void)ws_size; (void)n_in;

    const int B = in_sizes[0] / 256;               // 16384
    float* out = (float*)d_out;
    float* outsc = out + (size_t)B * 256;

    const int nblk = (B + NBATCH - 1) / NBATCH;    // 2731
    agm_kernel<<<dim3(nblk), dim3(512), 0, stream>>>(
        x, W_in, bin, ns, edge, W_rec, brec, W_sc, b_sc, out, outsc);
}